// Round 1
// 228.873 us; speedup vs baseline: 1.0109x; 1.0109x over previous
//
#include <hip/hip_runtime.h>

#define T_LEN 1024
#define NS    128
#define BT    16
#define G     16
#define SEG   32         // time segments per sequence (power of 2)
#define SSH   5          // log2(SEG)
#define NB    256        // total batches

typedef __attribute__((ext_vector_type(8))) short short8;
typedef __attribute__((ext_vector_type(4))) short short4v;
typedef __attribute__((ext_vector_type(4))) float f32x4;

static __device__ __forceinline__ short f2bf(float f) {   // RNE (one-time uses)
    unsigned u = __builtin_bit_cast(unsigned, f);
    u = (u + 0x7fffu + ((u >> 16) & 1u)) >> 16;
    return (short)u;
}
static __device__ __forceinline__ float bf2f(short s) {
    unsigned u = ((unsigned)(unsigned short)s) << 16;
    return __builtin_bit_cast(float, u);
}
static __device__ __forceinline__ short f2bf_trunc(float f) {  // in-loop: 1 op
    return (short)(__builtin_bit_cast(unsigned, f) >> 16);
}

// Segmented CRF forward:  out = log( r^T M_{L-1}...M_0 f0 ),  M_t = diag(eu_t) E.
// Same algorithm as prior round (rank-1 segment summaries, fwd 0..30 / bwd 1..31,
// 62 units x 16 groups).  THIS ROUND: unary no longer staged through LDS — each
// lane loads its own (batch bcol, rows w*32+quad*4(+16)) float4 pair straight
// from global (full 64B-line coalescing: 4 quads cover one line), with a true
// 2-deep register prefetch (manual unroll-2 keeps prefetch regs statically
// indexed).  LDS traffic/iter drops ~44% (was the binding per-CU pipe), LDS
// 24KB->8.3KB, and __launch_bounds__(256,4) targets 4 blocks/CU so all 992
// blocks are co-resident in one generation.
__global__ __launch_bounds__(256, 4) void crf_seg(
        const float* __restrict__ unary, const float* __restrict__ trans,
        const int* __restrict__ lengths,
        float* __restrict__ yv, float* __restrict__ zv,
        float* __restrict__ cfv, float* __restrict__ cbv) {
    __shared__ __align__(16) short Fs[2][BT * NS];   // bf16 state, XOR-swizzled chunks
    __shared__ int tbS[BT], teS[BT];
    __shared__ int itersS;

    const int tid = threadIdx.x;
    const int g = blockIdx.x & (G - 1);
    const int u = blockIdx.x >> 4;                    // 0..61
    const bool bwd = u >= (SEG - 1);
    const int s = bwd ? (u - (SEG - 2)) : u;          // fwd: 0..30 ; bwd: 1..31
    const int w = tid >> 6, lane = tid & 63;
    const int quad = lane >> 4, bcol = lane & 15;
    const int sr = tid >> 4, sc = tid & 15;           // init-staging row / col-chunk

    if (tid == 0) itersS = 0;
    if (tid < BT) {
        int L = lengths[g * BT + tid];
        tbS[tid] = (s * L) >> SSH;
        teS[tid] = ((s + 1) * L) >> SSH;
    }
    __syncthreads();
    if (tid < BT) atomicMax(&itersS, teS[tid] - tbS[tid]);

    const int tb = tbS[bcol], te = teS[bcol];
    const int nrec = te - tb - 1;                     // -1 => record happened at init
    const int s_tb = tbS[sr], s_te = teS[sr];

    // ---- A-fragments: E (fwd) or E^T (bwd), bf16, one-time ----
    short8 Ea[2][4];
    #pragma unroll
    for (int mt = 0; mt < 2; ++mt) {
        const int i = w * 32 + mt * 16 + bcol;        // A's m-index
        #pragma unroll
        for (int kt = 0; kt < 4; ++kt) {
            short8 e;
            if (!bwd) {
                const float* tr = trans + (size_t)i * NS + kt * 32 + quad * 8;
                float4 x = *(const float4*)tr, y = *(const float4*)(tr + 4);
                e[0] = f2bf(__expf(x.x)); e[1] = f2bf(__expf(x.y));
                e[2] = f2bf(__expf(x.z)); e[3] = f2bf(__expf(x.w));
                e[4] = f2bf(__expf(y.x)); e[5] = f2bf(__expf(y.y));
                e[6] = f2bf(__expf(y.z)); e[7] = f2bf(__expf(y.w));
            } else {
                #pragma unroll
                for (int jj = 0; jj < 8; ++jj)
                    e[jj] = f2bf(__expf(trans[(size_t)(kt * 32 + quad * 8 + jj) * NS + i]));
            }
            Ea[mt][kt] = e;
        }
    }

    // ---- init state into Fs[0] + init-records for empty segments ----
    {
        const float* ubase = unary + (size_t)(g * BT + sr) * T_LEN * NS + sc * 8;
        float v[8];
        if (!bwd) {
            #pragma unroll
            for (int k = 0; k < 8; ++k)
                v[k] = (s == 0) ? ((sc * 8 + k == 1) ? 1.f : 0.f) : 1.f;
        } else {
            int ti = s_te - 1; if (ti < 0) ti = 0;
            const float* up = ubase + (size_t)ti * NS;
            float4 ua = *(const float4*)up, ub4 = *(const float4*)(up + 4);
            float uu[8] = {ua.x, ua.y, ua.z, ua.w, ub4.x, ub4.y, ub4.z, ub4.w};
            #pragma unroll
            for (int k = 0; k < 8; ++k) {
                float vv = (s == SEG - 1) ? __expf(trans[2 * NS + sc * 8 + k]) : 1.f;
                v[k] = __expf(uu[k]) * vv;
            }
        }
        short8 z;
        #pragma unroll
        for (int k = 0; k < 8; ++k) z[k] = f2bf(v[k]);
        *(short8*)&Fs[0][sr * NS + ((sc ^ sr) << 3)] = z;

        if (s_te == s_tb) {   // empty segment: P = I, summary vector = init seed
            if (!bwd) {
                float* yp = yv + ((size_t)s * NB + g * BT + sr) * NS + sc * 8;
                #pragma unroll
                for (int k = 0; k < 8; ++k)
                    yp[k] = (s == 0) ? ((sc * 8 + k == 1) ? 1.f : 0.f) : 1.f;
                if (sc == 0) cfv[s * NB + g * BT + sr] = 0.f;
            } else {          // only middles can be empty; seed v = ones
                float* zp = zv + ((size_t)(s - 1) * NB + g * BT + sr) * NS + sc * 8;
                #pragma unroll
                for (int k = 0; k < 8; ++k) zp[k] = 1.f;
                if (sc == 0) cbv[(s - 1) * NB + g * BT + sr] = 0.f;
            }
        }
    }

    // ---- per-lane unary pointer (batch bcol, rows w*32+quad*4 / +16) ----
    const float* uptr = unary + (size_t)(g * BT + bcol) * T_LEN * NS + (w * 32 + quad * 4);
    #define T_OFB(nn) ({ int _t = bwd ? (te - 2 - (nn)) : (tb + (nn)); \
                         _t = _t < 0 ? 0 : (_t > T_LEN - 1 ? T_LEN - 1 : _t); _t; })
    float4 pA0, pA1, pB0, pB1;              // 2-deep prefetch (A: even n, B: odd n)
    { int t = T_OFB(0);
      pA0 = *(const float4*)(uptr + (size_t)t * NS);
      pA1 = *(const float4*)(uptr + (size_t)t * NS + 16); }
    { int t = T_OFB(1);
      pB0 = *(const float4*)(uptr + (size_t)t * NS);
      pB1 = *(const float4*)(uptr + (size_t)t * NS + 16); }
    __syncthreads();
    const int iters = itersS;

    // loop-invariant LDS offsets (R3-measured layout)
    int bfOff[4];
    #pragma unroll
    for (int kt = 0; kt < 4; ++kt) bfOff[kt] = bcol * NS + (((kt * 4 + quad) ^ bcol) << 3);
    const int s4Off = bcol * NS + (bcol << 3);                      // logical chunk 0
    const int c0 = w * 4 + (quad >> 1), half = (quad & 1) << 2;     // F write chunks
    const int fw0 = bcol * NS + ((c0 ^ bcol) << 3) + half;
    const int fw1 = bcol * NS + (((c0 + 2) ^ bcol) << 3) + half;

    float C = 0.f;

    // One CRF step.  U0/U1 are the (already loaded) unary float4s for this n;
    // after consuming them into exps we reload the SAME regs with t(n+2), so the
    // load issued here is first waited on two iterations later (true 2-deep).
#define STEP(U0, U1) do {                                                         \
    const int cur = n & 1, nxt = cur ^ 1;                                         \
    const short* fb = Fs[cur];                                                    \
    short8 Bf0 = *(const short8*)&fb[bfOff[0]];                                   \
    short8 Bf1 = *(const short8*)&fb[bfOff[1]];                                   \
    short8 Bf2 = *(const short8*)&fb[bfOff[2]];                                   \
    short8 Bf3 = *(const short8*)&fb[bfOff[3]];                                   \
    short4v s4 = *(const short4v*)&fb[s4Off];                                     \
    float e0[4], e1[4];                                                           \
    e0[0] = __expf(U0.x); e0[1] = __expf(U0.y);                                   \
    e0[2] = __expf(U0.z); e0[3] = __expf(U0.w);                                   \
    e1[0] = __expf(U1.x); e1[1] = __expf(U1.y);                                   \
    e1[2] = __expf(U1.z); e1[3] = __expf(U1.w);                                   \
    { int t = T_OFB(n + 2);                                                       \
      U0 = *(const float4*)(uptr + (size_t)t * NS);                               \
      U1 = *(const float4*)(uptr + (size_t)t * NS + 16); }                        \
    f32x4 x0 = {0.f,0.f,0.f,0.f}, y0 = {0.f,0.f,0.f,0.f};                         \
    f32x4 x1 = {0.f,0.f,0.f,0.f}, y1 = {0.f,0.f,0.f,0.f};                         \
    x0 = __builtin_amdgcn_mfma_f32_16x16x32_bf16(Ea[0][0], Bf0, x0, 0, 0, 0);     \
    x1 = __builtin_amdgcn_mfma_f32_16x16x32_bf16(Ea[1][0], Bf0, x1, 0, 0, 0);     \
    y0 = __builtin_amdgcn_mfma_f32_16x16x32_bf16(Ea[0][2], Bf2, y0, 0, 0, 0);     \
    y1 = __builtin_amdgcn_mfma_f32_16x16x32_bf16(Ea[1][2], Bf2, y1, 0, 0, 0);     \
    x0 = __builtin_amdgcn_mfma_f32_16x16x32_bf16(Ea[0][1], Bf1, x0, 0, 0, 0);     \
    x1 = __builtin_amdgcn_mfma_f32_16x16x32_bf16(Ea[1][1], Bf1, x1, 0, 0, 0);     \
    y0 = __builtin_amdgcn_mfma_f32_16x16x32_bf16(Ea[0][3], Bf3, y0, 0, 0, 0);     \
    y1 = __builtin_amdgcn_mfma_f32_16x16x32_bf16(Ea[1][3], Bf3, y1, 0, 0, 0);     \
    f32x4 a0 = x0 + y0, a1 = x1 + y1;                                             \
    float sv = (bf2f(s4[0]) + bf2f(s4[1])) + (bf2f(s4[2]) + bf2f(s4[3]));         \
    float rs = __fdividef(1.f, sv);                                               \
    float logs = __logf(sv);                                                      \
    float fn0[4], fn1[4];                                                         \
    fn0[0] = a0[0]*e0[0]*rs; fn0[1] = a0[1]*e0[1]*rs;                             \
    fn0[2] = a0[2]*e0[2]*rs; fn0[3] = a0[3]*e0[3]*rs;                             \
    fn1[0] = a1[0]*e1[0]*rs; fn1[1] = a1[1]*e1[1]*rs;                             \
    fn1[2] = a1[2]*e1[2]*rs; fn1[3] = a1[3]*e1[3]*rs;                             \
    if (n == nrec) {                                                              \
        if (!bwd) {   /* record normalized post-step state + C_after */           \
            float* yp = yv + ((size_t)s * NB + g * BT + bcol) * NS;               \
            *(float4*)(yp + w * 32 + quad * 4)      = (float4){fn0[0], fn0[1], fn0[2], fn0[3]}; \
            *(float4*)(yp + w * 32 + 16 + quad * 4) = (float4){fn1[0], fn1[1], fn1[2], fn1[3]}; \
            if (tid < BT) cfv[s * NB + g * BT + tid] = C + logs;                  \
        } else {      /* record RAW acc = E^T q (pre-eu) + C_before */            \
            float* zp = zv + ((size_t)(s - 1) * NB + g * BT + bcol) * NS;         \
            *(float4*)(zp + w * 32 + quad * 4)      = (float4){a0[0], a0[1], a0[2], a0[3]}; \
            *(float4*)(zp + w * 32 + 16 + quad * 4) = (float4){a1[0], a1[1], a1[2], a1[3]}; \
            if (tid < BT) cbv[(s - 1) * NB + g * BT + tid] = C;                   \
        }                                                                         \
    }                                                                             \
    C += logs;                                                                    \
    short4v p0, p1;                                                               \
    p0[0] = f2bf_trunc(fn0[0]); p0[1] = f2bf_trunc(fn0[1]);                       \
    p0[2] = f2bf_trunc(fn0[2]); p0[3] = f2bf_trunc(fn0[3]);                       \
    p1[0] = f2bf_trunc(fn1[0]); p1[1] = f2bf_trunc(fn1[1]);                       \
    p1[2] = f2bf_trunc(fn1[2]); p1[3] = f2bf_trunc(fn1[3]);                       \
    *(short4v*)&Fs[nxt][fw0] = p0;                                                \
    *(short4v*)&Fs[nxt][fw1] = p1;                                                \
    /* LDS-only barrier: global unary prefetch stays in flight (vmcnt not drained) */ \
    asm volatile("s_waitcnt lgkmcnt(0)" ::: "memory");                            \
    __builtin_amdgcn_s_barrier();                                                 \
} while (0)

    for (int n = 0; n < iters; ) {
        STEP(pA0, pA1); ++n;
        if (n >= iters) break;
        STEP(pB0, pB1); ++n;
    }
#undef STEP
#undef T_OFB
}

// out = Cf_0 + sum_{s=1..S-1} Cb_s + sum_{s=1..S-1} log(Z_s . Y_{s-1})
//       - sum_{s=1..S-2} log sum(Y_s)
__global__ __launch_bounds__(64) void crf_combine(
        const float* __restrict__ yv, const float* __restrict__ zv,
        const float* __restrict__ cfv, const float* __restrict__ cbv,
        float* __restrict__ out) {
    const int b = blockIdx.x, lane = threadIdx.x;
    float acc = cfv[b];
    for (int s = 1; s <= SEG - 1; ++s) acc += cbv[(s - 1) * NB + b];
    float lg = 0.f;
    for (int s = 1; s <= SEG - 1; ++s) {
        const float* Z = zv + ((size_t)(s - 1) * NB + b) * NS;
        const float* Y = yv + ((size_t)(s - 1) * NB + b) * NS;
        float d = Z[lane] * Y[lane] + Z[lane + 64] * Y[lane + 64];
        #pragma unroll
        for (int off = 1; off < 64; off <<= 1) d += __shfl_xor(d, off, 64);
        lg += __logf(d);
    }
    for (int s = 1; s <= SEG - 2; ++s) {
        const float* Y = yv + ((size_t)s * NB + b) * NS;
        float t = Y[lane] + Y[lane + 64];
        #pragma unroll
        for (int off = 1; off < 64; off <<= 1) t += __shfl_xor(t, off, 64);
        lg -= __logf(t);
    }
    if (lane == 0) out[b] = acc + lg;
}

extern "C" void kernel_launch(void* const* d_in, const int* in_sizes, int n_in,
                              void* d_out, int out_size, void* d_ws, size_t ws_size,
                              hipStream_t stream) {
    const float* unary   = (const float*)d_in[0];
    const float* trans   = (const float*)d_in[1];
    const int*   lengths = (const int*)d_in[2];
    float* out = (float*)d_out;

    float* yv  = (float*)d_ws;                          // [S-1][NB][NS]
    float* zv  = yv + (size_t)(SEG - 1) * NB * NS;      // [S-1][NB][NS]
    float* cfv = zv + (size_t)(SEG - 1) * NB * NS;      // [S-1][NB]
    float* cbv = cfv + (size_t)(SEG - 1) * NB;          // [S-1][NB]

    crf_seg<<<dim3(2 * (SEG - 1) * G), dim3(256), 0, stream>>>(
        unary, trans, lengths, yv, zv, cfv, cbv);
    crf_combine<<<dim3(NB), dim3(64), 0, stream>>>(yv, zv, cfv, cbv, out);
}